// Round 4
// baseline (209.818 us; speedup 1.0000x reference)
//
#include <hip/hip_runtime.h>
#include <hip/hip_bf16.h>

// Problem constants (SelectSphereConv, graph level 6)
#define VN 40962
#define KN 9
#define NGROUPS 5121      // ceil(VN/8), 8 vertices per wave-group
#define NBLK 1280         // grid; 2 waves-slots rounds: 10242 tasks / 5120 waves
#define NSLOT 2560        // wave slots per o-half = (NBLK/2)*4

typedef float f32x4 __attribute__((ext_vector_type(4)));
typedef float f32x16 __attribute__((ext_vector_type(16)));
typedef __bf16 bf16x8 __attribute__((ext_vector_type(8)));
typedef unsigned int u32x4 __attribute__((ext_vector_type(4)));

// ---------------------------------------------------------------------------
// Kernel 1: transpose x [256(t=b*64+c), V] f32 -> x_t [V, 256] bf16
// ---------------------------------------------------------------------------
__global__ __launch_bounds__(256) void k_transpose(const float* __restrict__ x,
                                                   __bf16* __restrict__ xt) {
    __shared__ __bf16 tile[64][65];
    const int v0 = blockIdx.x * 64;
    const int t0 = blockIdx.y * 64;
    const int lane = threadIdx.x & 63;
    const int sub = threadIdx.x >> 6;  // 0..3

#pragma unroll
    for (int r = 0; r < 16; ++r) {
        const int t = t0 + r * 4 + sub;
        const int v = v0 + lane;
        float val = (v < VN) ? x[(size_t)t * VN + v] : 0.f;  // coalesced
        tile[r * 4 + sub][lane] = (__bf16)val;
    }
    __syncthreads();
#pragma unroll
    for (int r = 0; r < 16; ++r) {
        const int vv = r * 4 + sub;
        const int v = v0 + vv;
        if (v < VN) xt[(size_t)v * 256 + t0 + lane] = tile[lane][vv];  // coalesced
    }
}

// ---------------------------------------------------------------------------
// Kernel 2: wave-autonomous fused gather + interpolate + conv.
//   GEMM contraction reordered k = j*64 + c so that for mfma_f32_32x32x16_bf16
//   step ks: j = ks>>2, c = 16*(ks&3) + 8*(lane>>5) + e  -- i.e. each lane's
//   interp outputs ARE its B-fragments. No LDS handoff, no main-loop barriers.
//   One wave owns 8 vertices (32 MFMA cols = 8 vv x 4 b) and 32 of 64 out
//   channels (o-half per block); interp is duplicated across the two halves.
//   Weights: pre-swizzled into fragment order in LDS once (36 KB), read as
//   contiguous ds_read_b128 (conflict-free).
// ---------------------------------------------------------------------------
__global__ __launch_bounds__(256) void k_fused(const __bf16* __restrict__ xt,
                                               const int* __restrict__ index,
                                               const float* __restrict__ itp_mat,
                                               const float* __restrict__ conv_w,
                                               const float* __restrict__ conv_b,
                                               float* __restrict__ out) {
    __shared__ char wlds[36 * 64 * 16];   // 36864 B: W frags [ks][lane][16B]

    const int tid  = threadIdx.x;
    const int lane = tid & 63;
    const int wv   = tid >> 6;
    const int l31  = lane & 31;
    const int h    = lane >> 5;     // k-half within a step
    const int b    = lane & 3;      // batch  (MFMA col = vv*4 + b = l31)
    const int vv   = l31 >> 2;      // vertex within group
    const int oh   = blockIdx.x & 1;   // which 32-wide o-half this block computes

    // ---- one-time: stage W fragments into LDS (frag-contiguous layout) ----
    {
        const int o = oh * 32 + l31;
#pragma unroll
        for (int t = 0; t < 9; ++t) {
            const int ks = wv * 9 + t;              // waves cover ks 0..35
            const int j  = ks >> 2;
            const int c0 = 16 * (ks & 3) + 8 * h;
            const float* wp = conv_w + (size_t)o * 576 + (size_t)c0 * 9 + j;
            bf16x8 f;
#pragma unroll
            for (int e = 0; e < 8; ++e) f[e] = (__bf16)wp[e * 9];  // c = c0+e
            *(bf16x8*)(wlds + ((size_t)ks * 64 + lane) * 16) = f;
        }
    }

    // ---- bias per accumulator register (D row = (r&3)+8*(r>>2)+4*h) ----
    float bias[16];
#pragma unroll
    for (int r = 0; r < 16; ++r) {
        const int ol = (r & 3) + 8 * (r >> 2) + 4 * h;
        bias[r] = conv_b[oh * 32 + ol];
    }
    __syncthreads();   // W-LDS ready; no barriers after this point

    const int slot = (blockIdx.x >> 1) * 4 + wv;

    for (int grp = slot; grp < NGROUPS; grp += NSLOT) {
        const int v0 = grp * 8;
        const int v  = v0 + vv;
        const int vm = (v < VN) ? v : VN - 1;        // clamp for tail group

        // neighbor ids for this lane's vertex (8 lanes share -> L1 broadcast)
        const int* idxp = index + (size_t)vm * KN;
        int nb[KN];
#pragma unroll
        for (int k = 0; k < KN; ++k) nb[k] = idxp[k];
        const float* amp = itp_mat + (size_t)vm * (KN * KN);

        f32x16 acc;
#pragma unroll
        for (int r = 0; r < 16; ++r) acc[r] = 0.f;

#pragma unroll 1
        for (int q = 0; q < 4; ++q) {               // c-block quadrant
            float s[8][9];                           // itp[c=8-block][j]
#pragma unroll
            for (int k = 0; k < KN; ++k) {
                // gather 8 channels (16B) of neighbor k for (b, c-block q, h)
                u32x4 gw = *(const u32x4*)((const char*)xt +
                            (size_t)nb[k] * 512 + b * 128 + q * 32 + h * 16);
                float g[8];
#pragma unroll
                for (int d = 0; d < 4; ++d) {
                    g[2 * d]     = __builtin_bit_cast(float, gw[d] << 16);
                    g[2 * d + 1] = __builtin_bit_cast(float, gw[d] & 0xffff0000u);
                }
#pragma unroll
                for (int j = 0; j < 9; ++j) {
                    const float a = amp[k * 9 + j];
#pragma unroll
                    for (int e = 0; e < 8; ++e) {
                        if (k == 0) s[e][j] = g[e] * a;
                        else        s[e][j] += g[e] * a;
                    }
                }
            }
            // 9 MFMAs for this quadrant: ks = 4*j + q
#pragma unroll
            for (int j = 0; j < 9; ++j) {
                bf16x8 bf;
#pragma unroll
                for (int e = 0; e < 8; ++e) bf[e] = (__bf16)s[e][j];
                const int ks = 4 * j + q;
                bf16x8 af = *(const bf16x8*)(wlds + ((size_t)ks * 64 + lane) * 16);
                acc = __builtin_amdgcn_mfma_f32_32x32x16_bf16(af, bf, acc, 0, 0, 0);
            }
        }

        // ---- store: out[(b*64 + o)*VN + v], o = oh*32 + rowmap(r,h) ----
        if (v < VN) {
            float* ob = out + (size_t)(b * 64 + oh * 32) * VN + v;
#pragma unroll
            for (int r = 0; r < 16; ++r) {
                const int ol = (r & 3) + 8 * (r >> 2) + 4 * h;
                ob[(size_t)ol * VN] = acc[r] + bias[r];
            }
        }
    }
}

// ---------------------------------------------------------------------------
extern "C" void kernel_launch(void* const* d_in, const int* in_sizes, int n_in,
                              void* d_out, int out_size, void* d_ws, size_t ws_size,
                              hipStream_t stream) {
    const float* x       = (const float*)d_in[0];
    const int*   index   = (const int*)d_in[1];
    const float* itp_mat = (const float*)d_in[2];
    const float* conv_w  = (const float*)d_in[3];
    const float* conv_b  = (const float*)d_in[4];
    float* out = (float*)d_out;

    __bf16* xt = (__bf16*)d_ws;   // VN*256*2 = 20,972,544 B of workspace

    dim3 tgrid((VN + 63) / 64, 4, 1);
    k_transpose<<<tgrid, 256, 0, stream>>>(x, xt);
    k_fused<<<NBLK, 256, 0, stream>>>(xt, index, itp_mat, conv_w, conv_b, out);
}

// Round 5
// 119.129 us; speedup vs baseline: 1.7613x; 1.7613x over previous
//
#include <hip/hip_runtime.h>
#include <hip/hip_bf16.h>

// Problem constants (SelectSphereConv, graph level 6)
#define VN 40962
#define KN 9
#define NG 10241          // ceil(VN/4): 4 vertices per group
#define GRID 512          // 2 blocks/CU
#define SA 1184           // A-tile row stride bytes (=74*16: aligned, <=4-way banks)
#define ITP_LAST (VN * 324 - 4)

// LDS map (bytes)
#define OFF_STAGE 0       // 2 bufs x 36 rows x 512
#define OFF_ITP   36864   // 2 bufs x 4 slots x 512
#define OFF_A     40960   // 16 x 1184 = 18944
#define OFF_C     59904   // 16 x 68 x 4 = 4352
#define LDS_TOT   64256

typedef float f32x4 __attribute__((ext_vector_type(4)));
typedef float f32x2 __attribute__((ext_vector_type(2)));
typedef __bf16 bf16x8 __attribute__((ext_vector_type(8)));
typedef unsigned short u16x4 __attribute__((ext_vector_type(4)));

#define GLL16(src, dst) __builtin_amdgcn_global_load_lds( \
    (const __attribute__((address_space(1))) unsigned int*)(src), \
    (__attribute__((address_space(3))) unsigned int*)(dst), 16, 0, 0)
#define GLL4(src, dst) __builtin_amdgcn_global_load_lds( \
    (const __attribute__((address_space(1))) unsigned int*)(src), \
    (__attribute__((address_space(3))) unsigned int*)(dst), 4, 0, 0)

__device__ __forceinline__ unsigned bf16b(float x) {
    __bf16 h = (__bf16)x;
    return (unsigned)__builtin_bit_cast(unsigned short, h);
}

// ---------------------------------------------------------------------------
// Kernel 1: transpose x [256(t=b*64+c), V] f32 -> x_t [V, 256] bf16
// ---------------------------------------------------------------------------
__global__ __launch_bounds__(256) void k_transpose(const float* __restrict__ x,
                                                   __bf16* __restrict__ xt) {
    __shared__ __bf16 tile[64][65];
    const int v0 = blockIdx.x * 64;
    const int t0 = blockIdx.y * 64;
    const int lane = threadIdx.x & 63;
    const int sub = threadIdx.x >> 6;

#pragma unroll
    for (int r = 0; r < 16; ++r) {
        const int t = t0 + r * 4 + sub;
        const int v = v0 + lane;
        float val = (v < VN) ? x[(size_t)t * VN + v] : 0.f;
        tile[r * 4 + sub][lane] = (__bf16)val;
    }
    __syncthreads();
#pragma unroll
    for (int r = 0; r < 16; ++r) {
        const int vv = r * 4 + sub;
        const int v = v0 + vv;
        if (v < VN) xt[(size_t)v * 256 + t0 + lane] = tile[lane][vv];
    }
}

// ---------------------------------------------------------------------------
// Kernel 2: fused, fully async-staged.
//  Per group (4 vertices): 36 neighbor rows (512B each) + 4 itp_mat rows are
//  staged to LDS one group ahead via global_load_lds (wave-coalesced, counted
//  vmcnt(8) -- never drained mid-loop). Neighbor ids prefetched 2 groups
//  ahead to registers. Wave w interps vertex w (lane owns 4 t-cols, 324 FMA,
//  itp coeffs via broadcast ds_read_b128), writes 16-row A-tile; MFMA with
//  register W-frags (wave w owns o-tile w); C via LDS, stores deferred.
// ---------------------------------------------------------------------------
__global__ __launch_bounds__(256) void k_fused(const __bf16* __restrict__ xt,
                                               const int* __restrict__ index,
                                               const float* __restrict__ itp_mat,
                                               const float* __restrict__ conv_w,
                                               const float* __restrict__ conv_b,
                                               float* __restrict__ out) {
    __shared__ char smem[LDS_TOT];

    const int tid  = threadIdx.x;
    const int lane = tid & 63;
    const int w    = __builtin_amdgcn_readfirstlane(tid >> 6);
    const int l16  = lane & 15;
    const int g4   = lane >> 4;
    const int kb   = g4 * 8;

    // ---- W fragments in registers: 18 ksteps x 8 bf16 = 72 VGPR ----
    bf16x8 wfrag[18];
    {
        const int o = w * 16 + l16;
        const float* wrow = conv_w + (size_t)o * 576;
#pragma unroll
        for (int ks = 0; ks < 18; ++ks) {
            f32x4 w0 = *(const f32x4*)(wrow + ks * 32 + kb);
            f32x4 w1 = *(const f32x4*)(wrow + ks * 32 + kb + 4);
            bf16x8 f;
            f[0] = (__bf16)w0[0]; f[1] = (__bf16)w0[1];
            f[2] = (__bf16)w0[2]; f[3] = (__bf16)w0[3];
            f[4] = (__bf16)w1[0]; f[5] = (__bf16)w1[1];
            f[6] = (__bf16)w1[2]; f[7] = (__bf16)w1[3];
            wfrag[ks] = f;
        }
    }
    const float bias_v = conv_b[lane];          // thread t: o = t&63 = lane

    // gll row-pair assignment: wave w issues pairs [pstart, pstart+pcnt)
    const int pstart = __builtin_amdgcn_readfirstlane((w * 9 + (w & 1)) / 2); // 0,5,9,14
    const int pcnt   = __builtin_amdgcn_readfirstlane(5 - (w & 1));           // 5,4,5,4

    int g = blockIdx.x;
    int ra0[5], rb0[5], ra1[5], rb1[5];

    // ---- prologue: stage group g into buf0; preload ids for g+GRID ----
    {
        const int b0v = (g * 4 < VN - 4) ? g * 4 : VN - 4;
        const int* ip = index + (size_t)b0v * 9;
        char* sb0 = smem + OFF_STAGE;
        char* ib0 = smem + OFF_ITP;
#pragma unroll
        for (int i = 0; i < 5; ++i) if (i < pcnt) {
            const int p = pstart + i;
            const int rav = ip[2 * p], rbv = ip[2 * p + 1];
            const int rsel = (lane < 32) ? rav : rbv;
            GLL16((const char*)xt + (size_t)rsel * 512 + (lane & 31) * 16,
                  sb0 + p * 1024);
        }
        size_t o1 = (size_t)(b0v + w) * 324 + lane * 4;
        GLL4((const char*)itp_mat + o1, ib0 + w * 512);
        size_t o2 = o1 + 256; if (o2 > ITP_LAST) o2 = ITP_LAST;
        GLL4((const char*)itp_mat + o2, ib0 + w * 512 + 256);

        const int g1 = (g + GRID < NG) ? g + GRID : NG - 1;
        const int b1v = (g1 * 4 < VN - 4) ? g1 * 4 : VN - 4;
        const int* ip1 = index + (size_t)b1v * 9;
#pragma unroll
        for (int i = 0; i < 5; ++i) if (i < pcnt) {
            ra0[i] = ip1[2 * (pstart + i)];
            rb0[i] = ip1[2 * (pstart + i) + 1];
        }
    }

    bool havePrev = false;
    int vprev = 0;

#define STORE_PREV() {                                                        \
    float* cb = (float*)(smem + OFF_C);                                       \
    f32x4 vals;                                                               \
    _Pragma("unroll")                                                         \
    for (int e = 0; e < 4; ++e) vals[e] = cb[(e * 4 + w) * 68 + lane] + bias_v;\
    float* op = out + (size_t)tid * VN + vprev;                               \
    if (vprev + 3 < VN) {                                                     \
        *(f32x2*)op       = f32x2{vals[0], vals[1]};                          \
        *(f32x2*)(op + 2) = f32x2{vals[2], vals[3]};                          \
    } else {                                                                  \
        _Pragma("unroll")                                                     \
        for (int e = 0; e < 4; ++e) if (vprev + e < VN) op[e] = vals[e];      \
    } }

#define BODY(P, RAc, RBc, RAn, RBn) {                                         \
    const int gn = g + GRID;                                                  \
    if (gn < NG) {                                                            \
        const int bn = (gn * 4 < VN - 4) ? gn * 4 : VN - 4;                   \
        char* sb1 = smem + OFF_STAGE + ((P) ^ 1) * 18432;                     \
        char* ib1 = smem + OFF_ITP + ((P) ^ 1) * 2048;                        \
        _Pragma("unroll")                                                     \
        for (int i = 0; i < 5; ++i) if (i < pcnt) {                           \
            const int p = pstart + i;                                         \
            const int rsel = (lane < 32) ? RAc[i] : RBc[i];                   \
            GLL16((const char*)xt + (size_t)rsel * 512 + (lane & 31) * 16,    \
                  sb1 + p * 1024);                                            \
        }                                                                     \
        { size_t o1 = (size_t)(bn + w) * 324 + lane * 4;                      \
          GLL4((const char*)itp_mat + o1, ib1 + w * 512);                     \
          size_t o2 = o1 + 256; if (o2 > ITP_LAST) o2 = ITP_LAST;             \
          GLL4((const char*)itp_mat + o2, ib1 + w * 512 + 256); }             \
        const int gn2 = g + 2 * GRID;                                         \
        const int gc = (gn2 < NG) ? gn2 : NG - 1;                             \
        const int bn2 = (gc * 4 < VN - 4) ? gc * 4 : VN - 4;                  \
        const int* ip2 = index + (size_t)bn2 * 9;                             \
        _Pragma("unroll")                                                     \
        for (int i = 0; i < 5; ++i) if (i < pcnt) {                           \
            RAn[i] = ip2[2 * (pstart + i)];                                   \
            RBn[i] = ip2[2 * (pstart + i) + 1];                               \
        }                                                                     \
        asm volatile("s_waitcnt vmcnt(8)" ::: "memory");                      \
    } else {                                                                  \
        asm volatile("s_waitcnt vmcnt(0)" ::: "memory");                      \
    }                                                                         \
    asm volatile("s_waitcnt lgkmcnt(0)" ::: "memory");                        \
    __builtin_amdgcn_s_barrier();  /* D: stage(g) visible, A-tile/C free */   \
    if (havePrev) STORE_PREV();                                               \
    { /* E: interp vertex w from staged data */                               \
        const int base_g = (g * 4 < VN - 4) ? g * 4 : VN - 4;                 \
        int vme = g * 4 + w; if (vme > VN - 1) vme = VN - 1;                  \
        const int slot = vme - base_g;                                        \
        const char* sb = smem + OFF_STAGE + (P) * 18432;                      \
        const char* ib = smem + OFF_ITP + (P) * 2048 + slot * 512;            \
        float gv[4][9];                                                       \
        _Pragma("unroll")                                                     \
        for (int k = 0; k < 9; ++k) {                                         \
            u16x4 raw = *(const u16x4*)(sb + (slot * 9 + k) * 512 + lane * 8);\
            _Pragma("unroll")                                                 \
            for (int e = 0; e < 4; ++e)                                       \
                gv[e][k] = __builtin_bit_cast(float, (unsigned)raw[e] << 16); \
        }                                                                     \
        float s[4][9];                                                        \
        _Pragma("unroll")                                                     \
        for (int e = 0; e < 4; ++e)                                           \
            _Pragma("unroll")                                                 \
            for (int j = 0; j < 9; ++j) s[e][j] = 0.f;                        \
        _Pragma("unroll")                                                     \
        for (int m = 0; m < 21; ++m) {                                        \
            f32x4 amc = *(const f32x4*)(ib + m * 16);                         \
            _Pragma("unroll")                                                 \
            for (int e2 = 0; e2 < 4; ++e2) {                                  \
                const int f = 4 * m + e2;                                     \
                if (f < 81) {                                                 \
                    const int kk = f / 9, jj = f % 9;                         \
                    _Pragma("unroll")                                         \
                    for (int e = 0; e < 4; ++e)                               \
                        s[e][jj] += gv[e][kk] * amc[e2];                      \
                }                                                             \
            }                                                                 \
        }                                                                     \
        char* aw = smem + OFF_A + (w * 4 + g4) * SA + l16 * 72;               \
        _Pragma("unroll")                                                     \
        for (int q = 0; q < 18; ++q) {                                        \
            const int i0 = 2 * q, i1 = 2 * q + 1;                             \
            unsigned lo = bf16b(s[i0 / 9][i0 % 9]);                           \
            unsigned hi = bf16b(s[i1 / 9][i1 % 9]);                           \
            *(unsigned*)(aw + 4 * q) = lo | (hi << 16);                       \
        }                                                                     \
    }                                                                         \
    asm volatile("s_waitcnt lgkmcnt(0)" ::: "memory");                        \
    __builtin_amdgcn_s_barrier();  /* F: A-tile ready */                      \
    { /* G: MFMA + C-buf write */                                             \
        f32x4 acc = {0.f, 0.f, 0.f, 0.f};                                     \
        const char* ar = smem + OFF_A + l16 * SA + g4 * 16;                   \
        _Pragma("unroll")                                                     \
        for (int ks = 0; ks < 18; ++ks) {                                     \
            bf16x8 a = *(const bf16x8*)(ar + ks * 64);                        \
            acc = __builtin_amdgcn_mfma_f32_16x16x32_bf16(a, wfrag[ks], acc, 0, 0, 0); \
        }                                                                     \
        float* cb = (float*)(smem + OFF_C);                                   \
        _Pragma("unroll")                                                     \
        for (int r = 0; r < 4; ++r)                                           \
            cb[(g4 * 4 + r) * 68 + w * 16 + l16] = acc[r];                    \
    }                                                                         \
    havePrev = true; vprev = g * 4;                                           \
}

    while (g < NG) {
        BODY(0, ra0, rb0, ra1, rb1);
        g += GRID;
        if (g >= NG) break;
        BODY(1, ra1, rb1, ra0, rb0);
        g += GRID;
    }

    // ---- epilogue: store final group's C ----
    asm volatile("s_waitcnt lgkmcnt(0)" ::: "memory");
    __builtin_amdgcn_s_barrier();
    if (havePrev) STORE_PREV();
#undef BODY
#undef STORE_PREV
}

// ---------------------------------------------------------------------------
extern "C" void kernel_launch(void* const* d_in, const int* in_sizes, int n_in,
                              void* d_out, int out_size, void* d_ws, size_t ws_size,
                              hipStream_t stream) {
    const float* x       = (const float*)d_in[0];
    const int*   index   = (const int*)d_in[1];
    const float* itp_mat = (const float*)d_in[2];
    const float* conv_w  = (const float*)d_in[3];
    const float* conv_b  = (const float*)d_in[4];
    float* out = (float*)d_out;

    __bf16* xt = (__bf16*)d_ws;   // VN*256*2 = 20,972,544 B of workspace

    dim3 tgrid((VN + 63) / 64, 4, 1);
    k_transpose<<<tgrid, 256, 0, stream>>>(x, xt);
    k_fused<<<GRID, 256, 0, stream>>>(xt, index, itp_mat, conv_w, conv_b, out);
}